// Round 2
// baseline (121.663 us; speedup 1.0000x reference)
//
#include <hip/hip_runtime.h>
#include <hip/hip_cooperative_groups.h>

namespace cg = cooperative_groups;

// Problem constants (fixed by setup_inputs)
#define B 4
#define C 32
#define H 128
#define W 128
#define K 128
#define V 16           // C/2 vertices
#define HW (H * W)
#define OFFSET 100.0f

// One cooperative launch: 512 blocks (one per polygon pair) x 128 threads
// (one per scanline row). Each block computes iou*mask for its polygon into
// ws[bk]; grid.sync(); block 0 reduces 512 values + mask sum -> loss scalar.
__global__ __launch_bounds__(128) void fused_poly_iou_kernel(
    const float* __restrict__ output,   // [B,C,H,W]
    const int*   __restrict__ mask,     // [B,K] (flat 512)
    const int*   __restrict__ ind,      // [B,K]
    const float* __restrict__ target,   // [B,C,K]
    float* __restrict__ ws,             // [B*K] scratch
    float* __restrict__ out)            // [1] loss
{
    const int bk  = blockIdx.x;
    const int b   = bk >> 7;        // / K
    const int k   = bk & (K - 1);
    const int tid = threadIdx.x;

    __shared__ float sxp[V], syp[V], sxg[V], syg[V];
    __shared__ int   s_acc[3];   // pin_sum, gin_sum, inter_sum

    if (tid < 3) s_acc[tid] = 0;

    if (tid < C) {
        // pred vertices: gather output[b, c, ind[b,k]]
        const int idx = ind[bk];
        const float val = truncf(output[((size_t)b * C + tid) * HW + idx]) + OFFSET;
        if (tid & 1) syp[tid >> 1] = val; else sxp[tid >> 1] = val;
    } else if (tid < 2 * C) {
        const int c = tid - C;
        const float val = truncf(target[((size_t)b * C + c) * K + k]) + OFFSET;
        if (c & 1) syg[c >> 1] = val; else sxg[c >> 1] = val;
    }
    __syncthreads();

    const float pyf = (float)tid;   // scanline row
    unsigned long long pl0 = 0, pl1 = 0, gl0 = 0, gl1 = 0;

    #pragma unroll
    for (int v = 0; v < V; ++v) {
        const int v2 = (v + 1) & (V - 1);
        // pred polygon edge
        {
            const float y1 = syp[v], y2 = syp[v2];
            if ((y1 <= pyf) != (y2 <= pyf)) {
                const float x1 = sxp[v], x2 = sxp[v2];
                const float t  = __fdiv_rn(pyf - y1, y2 - y1);
                const float xi = __fadd_rn(x1, __fmul_rn(t, x2 - x1));
                int n = (int)ceilf(xi);
                n = n < 0 ? 0 : (n > 128 ? 128 : n);
                pl0 ^= (n >= 64) ? ~0ull : ((1ull << n) - 1ull);
                pl1 ^= (n <= 64) ? 0ull : ((n >= 128) ? ~0ull : ((1ull << (n - 64)) - 1ull));
            }
        }
        // gt polygon edge
        {
            const float y1 = syg[v], y2 = syg[v2];
            if ((y1 <= pyf) != (y2 <= pyf)) {
                const float x1 = sxg[v], x2 = sxg[v2];
                const float t  = __fdiv_rn(pyf - y1, y2 - y1);
                const float xi = __fadd_rn(x1, __fmul_rn(t, x2 - x1));
                int n = (int)ceilf(xi);
                n = n < 0 ? 0 : (n > 128 ? 128 : n);
                gl0 ^= (n >= 64) ? ~0ull : ((1ull << n) - 1ull);
                gl1 ^= (n <= 64) ? 0ull : ((n >= 128) ? ~0ull : ((1ull << (n - 64)) - 1ull));
            }
        }
    }

    int pin = __popcll(pl0) + __popcll(pl1);
    int gin = __popcll(gl0) + __popcll(gl1);
    int itr = __popcll(pl0 & gl0) + __popcll(pl1 & gl1);

    // wave-64 butterfly, then 2-wave combine via LDS atomics
    #pragma unroll
    for (int off = 32; off; off >>= 1) {
        pin += __shfl_down(pin, off, 64);
        gin += __shfl_down(gin, off, 64);
        itr += __shfl_down(itr, off, 64);
    }
    if ((tid & 63) == 0) {
        atomicAdd(&s_acc[0], pin);
        atomicAdd(&s_acc[1], gin);
        atomicAdd(&s_acc[2], itr);
    }
    __syncthreads();

    if (tid == 0) {
        const float inter = (float)s_acc[2];
        const float uni   = (float)(s_acc[0] + s_acc[1]) - inter;
        const float iou   = inter / (uni + 0.0001f);
        ws[bk] = iou * (float)mask[bk];
    }

    // grid-wide barrier (cooperative launch); includes device-scope fence
    cg::this_grid().sync();

    if (bk == 0) {
        float s = 0.0f, m = 0.0f;
        #pragma unroll
        for (int i = 0; i < 4; ++i) {
            const int j = tid + i * 128;
            s += ws[j];
            m += (float)mask[j];
        }
        #pragma unroll
        for (int off = 32; off; off >>= 1) {
            s += __shfl_down(s, off, 64);
            m += __shfl_down(m, off, 64);
        }
        __shared__ float ss[2], sm[2];
        if ((tid & 63) == 0) { ss[tid >> 6] = s; sm[tid >> 6] = m; }
        __syncthreads();
        if (tid == 0) {
            out[0] = 1.0f - (ss[0] + ss[1]) / (sm[0] + sm[1] + 0.0001f);
        }
    }
}

extern "C" void kernel_launch(void* const* d_in, const int* in_sizes, int n_in,
                              void* d_out, int out_size, void* d_ws, size_t ws_size,
                              hipStream_t stream) {
    const float* output = (const float*)d_in[0];
    const int*   mask   = (const int*)d_in[1];
    const int*   ind    = (const int*)d_in[2];
    const float* target = (const float*)d_in[3];
    float*       ws     = (float*)d_ws;
    float*       out    = (float*)d_out;

    void* args[] = {(void*)&output, (void*)&mask, (void*)&ind, (void*)&target,
                    (void*)&ws, (void*)&out};
    hipLaunchCooperativeKernel((const void*)fused_poly_iou_kernel,
                               dim3(B * K), dim3(128), args, 0, stream);
}

// Round 4
// 90.164 us; speedup vs baseline: 1.3494x; 1.3494x over previous
//
#include <hip/hip_runtime.h>

// Problem constants (fixed by setup_inputs)
#define B 4
#define C 32
#define H 128
#define W 128
#define K 128
#define V 16           // C/2 vertices
#define HW (H * W)
#define OFFSET 100.0f

// One block per polygon pair (pred, gt), 64 threads = 1 wave, 2 scanline rows
// per thread. Even-odd parity masks per row via XOR of 128-bit prefix masks,
// popcount -> per-polygon IoU. Block atomically accumulates S=sum(iou*m),
// M=sum(m) into acc[]; the last block to finish (ticket) computes the loss.
__global__ __launch_bounds__(64) void poly_iou_kernel(
    const float* __restrict__ output,   // [B,C,H,W]
    const int*   __restrict__ mask,     // [B,K] flat 512
    const int*   __restrict__ ind,      // [B,K]
    const float* __restrict__ target,   // [B,C,K]
    float* __restrict__ acc,            // ws: [0]=S, [1]=M, (int)[2]=ticket (zeroed)
    float* __restrict__ out)            // [1] loss
{
    const int bk  = blockIdx.x;
    const int b   = bk >> 7;        // / K
    const int k   = bk & (K - 1);
    const int tid = threadIdx.x;

    __shared__ float sxp[V], syp[V], sxg[V], syg[V];

    if (tid < C) {
        // pred vertices: gather output[b, c, ind[b,k]]
        const int idx = ind[bk];
        const float val = truncf(output[((size_t)b * C + tid) * HW + idx]) + OFFSET;
        if (tid & 1) syp[tid >> 1] = val; else sxp[tid >> 1] = val;
    } else {
        const int c = tid - C;
        const float val = truncf(target[((size_t)b * C + c) * K + k]) + OFFSET;
        if (c & 1) syg[c >> 1] = val; else sxg[c >> 1] = val;
    }
    __syncthreads();   // single wave: compiles to an LDS waitcnt, cheap

    int pin = 0, gin = 0, itr = 0;

    #pragma unroll
    for (int rr = 0; rr < 2; ++rr) {
        const float pyf = (float)(tid + rr * 64);   // scanline row
        unsigned long long pl0 = 0, pl1 = 0, gl0 = 0, gl1 = 0;

        #pragma unroll
        for (int v = 0; v < V; ++v) {
            const int v2 = (v + 1) & (V - 1);
            // pred polygon edge
            {
                const float y1 = syp[v], y2 = syp[v2];
                if ((y1 <= pyf) != (y2 <= pyf)) {
                    const float x1 = sxp[v], x2 = sxp[v2];
                    const float t  = __fdiv_rn(pyf - y1, y2 - y1);
                    const float xi = __fadd_rn(x1, __fmul_rn(t, x2 - x1));
                    int n = (int)ceilf(xi);
                    n = n < 0 ? 0 : (n > 128 ? 128 : n);
                    pl0 ^= (n >= 64) ? ~0ull : ((1ull << n) - 1ull);
                    pl1 ^= (n <= 64) ? 0ull : ((n >= 128) ? ~0ull : ((1ull << (n - 64)) - 1ull));
                }
            }
            // gt polygon edge
            {
                const float y1 = syg[v], y2 = syg[v2];
                if ((y1 <= pyf) != (y2 <= pyf)) {
                    const float x1 = sxg[v], x2 = sxg[v2];
                    const float t  = __fdiv_rn(pyf - y1, y2 - y1);
                    const float xi = __fadd_rn(x1, __fmul_rn(t, x2 - x1));
                    int n = (int)ceilf(xi);
                    n = n < 0 ? 0 : (n > 128 ? 128 : n);
                    gl0 ^= (n >= 64) ? ~0ull : ((1ull << n) - 1ull);
                    gl1 ^= (n <= 64) ? 0ull : ((n >= 128) ? ~0ull : ((1ull << (n - 64)) - 1ull));
                }
            }
        }

        pin += __popcll(pl0) + __popcll(pl1);
        gin += __popcll(gl0) + __popcll(gl1);
        itr += __popcll(pl0 & gl0) + __popcll(pl1 & gl1);
    }

    // wave-64 butterfly reduction
    #pragma unroll
    for (int off = 32; off; off >>= 1) {
        pin += __shfl_down(pin, off, 64);
        gin += __shfl_down(gin, off, 64);
        itr += __shfl_down(itr, off, 64);
    }

    if (tid == 0) {
        const float inter = (float)itr;
        const float uni   = (float)(pin + gin) - inter;
        const float iou   = inter / (uni + 0.0001f);
        const float m     = (float)mask[bk];

        atomicAdd(&acc[0], iou * m);     // S
        atomicAdd(&acc[1], m);           // M
        __threadfence();                 // release: S/M adds visible before ticket
        const int old = atomicAdd((int*)&acc[2], 1);
        if (old == B * K - 1) {
            __threadfence();             // acquire: see all other blocks' adds
            const float S = __hip_atomic_load(&acc[0], __ATOMIC_RELAXED, __HIP_MEMORY_SCOPE_AGENT);
            const float M = __hip_atomic_load(&acc[1], __ATOMIC_RELAXED, __HIP_MEMORY_SCOPE_AGENT);
            out[0] = 1.0f - S / (M + 0.0001f);
        }
    }
}

extern "C" void kernel_launch(void* const* d_in, const int* in_sizes, int n_in,
                              void* d_out, int out_size, void* d_ws, size_t ws_size,
                              hipStream_t stream) {
    const float* output = (const float*)d_in[0];
    const int*   mask   = (const int*)d_in[1];
    const int*   ind    = (const int*)d_in[2];
    const float* target = (const float*)d_in[3];
    float*       acc    = (float*)d_ws;   // 16 B: S, M, ticket, pad
    float*       out    = (float*)d_out;

    hipMemsetAsync(acc, 0, 16, stream);   // zero accumulators + ticket
    poly_iou_kernel<<<B * K, 64, 0, stream>>>(output, mask, ind, target, acc, out);
}

// Round 5
// 71.682 us; speedup vs baseline: 1.6973x; 1.2578x over previous
//
#include <hip/hip_runtime.h>

// Problem constants (fixed by setup_inputs)
#define B 4
#define C 32
#define H 128
#define W 128
#define K 128
#define V 16           // C/2 vertices
#define HW (H * W)
#define OFFSET 100.0f

// Kernel A: one block per polygon pair (pred, gt), 64 threads = 1 wave,
// 2 scanline rows per thread. Even-odd parity masks per row via XOR of
// 128-bit prefix masks, popcount -> per-polygon IoU; writes iou*mask to ws.
__global__ __launch_bounds__(64) void poly_iou_kernel(
    const float* __restrict__ output,   // [B,C,H,W]
    const int*   __restrict__ mask,     // [B,K] flat 512
    const int*   __restrict__ ind,      // [B,K]
    const float* __restrict__ target,   // [B,C,K]
    float* __restrict__ poly_out)       // [B*K]
{
    const int bk  = blockIdx.x;
    const int b   = bk >> 7;        // / K
    const int k   = bk & (K - 1);
    const int tid = threadIdx.x;

    __shared__ float sxp[V], syp[V], sxg[V], syg[V];

    if (tid < C) {
        // pred vertices: gather output[b, c, ind[b,k]]
        const int idx = ind[bk];
        const float val = truncf(output[((size_t)b * C + tid) * HW + idx]) + OFFSET;
        if (tid & 1) syp[tid >> 1] = val; else sxp[tid >> 1] = val;
    } else {
        const int c = tid - C;
        const float val = truncf(target[((size_t)b * C + c) * K + k]) + OFFSET;
        if (c & 1) syg[c >> 1] = val; else sxg[c >> 1] = val;
    }
    __syncthreads();   // single wave: cheap (lgkmcnt drain)

    int pin = 0, gin = 0, itr = 0;

    #pragma unroll
    for (int rr = 0; rr < 2; ++rr) {
        const float pyf = (float)(tid + rr * 64);   // scanline row
        unsigned long long pl0 = 0, pl1 = 0, gl0 = 0, gl1 = 0;

        #pragma unroll
        for (int v = 0; v < V; ++v) {
            const int v2 = (v + 1) & (V - 1);
            // pred polygon edge
            {
                const float y1 = syp[v], y2 = syp[v2];
                if ((y1 <= pyf) != (y2 <= pyf)) {
                    const float x1 = sxp[v], x2 = sxp[v2];
                    const float t  = __fdiv_rn(pyf - y1, y2 - y1);
                    const float xi = __fadd_rn(x1, __fmul_rn(t, x2 - x1));
                    int n = (int)ceilf(xi);
                    n = n < 0 ? 0 : (n > 128 ? 128 : n);
                    pl0 ^= (n >= 64) ? ~0ull : ((1ull << n) - 1ull);
                    pl1 ^= (n <= 64) ? 0ull : ((n >= 128) ? ~0ull : ((1ull << (n - 64)) - 1ull));
                }
            }
            // gt polygon edge
            {
                const float y1 = syg[v], y2 = syg[v2];
                if ((y1 <= pyf) != (y2 <= pyf)) {
                    const float x1 = sxg[v], x2 = sxg[v2];
                    const float t  = __fdiv_rn(pyf - y1, y2 - y1);
                    const float xi = __fadd_rn(x1, __fmul_rn(t, x2 - x1));
                    int n = (int)ceilf(xi);
                    n = n < 0 ? 0 : (n > 128 ? 128 : n);
                    gl0 ^= (n >= 64) ? ~0ull : ((1ull << n) - 1ull);
                    gl1 ^= (n <= 64) ? 0ull : ((n >= 128) ? ~0ull : ((1ull << (n - 64)) - 1ull));
                }
            }
        }

        pin += __popcll(pl0) + __popcll(pl1);
        gin += __popcll(gl0) + __popcll(gl1);
        itr += __popcll(pl0 & gl0) + __popcll(pl1 & gl1);
    }

    // wave-64 butterfly reduction
    #pragma unroll
    for (int off = 32; off; off >>= 1) {
        pin += __shfl_down(pin, off, 64);
        gin += __shfl_down(gin, off, 64);
        itr += __shfl_down(itr, off, 64);
    }

    if (tid == 0) {
        const float inter = (float)itr;
        const float uni   = (float)(pin + gin) - inter;
        const float iou   = inter / (uni + 0.0001f);
        poly_out[bk] = iou * (float)mask[bk];
    }
}

// Kernel B: 1 block x 64 threads reduces 512 iou*m values + mask sum -> loss.
__global__ __launch_bounds__(64) void finalize_kernel(
    const float* __restrict__ poly,   // [B*K]
    const int*   __restrict__ mask,   // [B*K]
    float* __restrict__ out)
{
    const int tid = threadIdx.x;      // 64 threads, 8 polygons each
    const float4* p4 = (const float4*)poly;
    const int4*   m4 = (const int4*)mask;

    float s = 0.0f, m = 0.0f;
    #pragma unroll
    for (int i = 0; i < 2; ++i) {
        const float4 pv = p4[tid * 2 + i];
        const int4   mv = m4[tid * 2 + i];
        s += pv.x + pv.y + pv.z + pv.w;
        m += (float)(mv.x + mv.y + mv.z + mv.w);
    }

    #pragma unroll
    for (int off = 32; off; off >>= 1) {
        s += __shfl_down(s, off, 64);
        m += __shfl_down(m, off, 64);
    }

    if (tid == 0) out[0] = 1.0f - s / (m + 0.0001f);
}

extern "C" void kernel_launch(void* const* d_in, const int* in_sizes, int n_in,
                              void* d_out, int out_size, void* d_ws, size_t ws_size,
                              hipStream_t stream) {
    const float* output = (const float*)d_in[0];
    const int*   mask   = (const int*)d_in[1];
    const int*   ind    = (const int*)d_in[2];
    const float* target = (const float*)d_in[3];

    float* poly = (float*)d_ws;   // [B*K] floats scratch, fully overwritten each call

    poly_iou_kernel<<<B * K, 64, 0, stream>>>(output, mask, ind, target, poly);
    finalize_kernel<<<1, 64, 0, stream>>>(poly, mask, (float*)d_out);
}